// Round 1
// baseline (196.800 us; speedup 1.0000x reference)
//
#include <hip/hip_runtime.h>
#include <hip/hip_bf16.h>

#define BATCH 2
#define SEQ 2048
#define DMODEL 768
#define NHEADS 12
#define NKV 4
#define DHEAD 64
#define WIN 512
#define GLB 64
#define ROWS (BATCH * SEQ)  // 4096

typedef short short8 __attribute__((ext_vector_type(8)));
typedef float f32x4 __attribute__((ext_vector_type(4)));

// fp32 -> bf16 bits, round-to-nearest-even (finite inputs only)
__device__ inline short f2bs(float f) {
    unsigned u = __float_as_uint(f);
    return (short)((u + 0x7fffu + ((u >> 16) & 1u)) >> 16);
}

// ---------------------------------------------------------------------------
// All four weight transposes in one launch: w[768,N] fp32 -> wT[N,768] bf16.
// ---------------------------------------------------------------------------
__global__ __launch_bounds__(256) void transp_all(
    const float* __restrict__ wq, const float* __restrict__ wk,
    const float* __restrict__ wv, const float* __restrict__ wo,
    short* __restrict__ wqkvT, short* __restrict__ woT) {
    __shared__ float t[32][33];
    int bid = blockIdx.x;
    const float* src; short* dst; int N;
    if (bid < 576)      { src = wq; dst = wqkvT; N = DMODEL; }
    else if (bid < 768) { src = wk; dst = wqkvT + DMODEL * DMODEL; N = 256; bid -= 576; }
    else if (bid < 960) { src = wv; dst = wqkvT + (DMODEL + 256) * DMODEL; N = 256; bid -= 768; }
    else                { src = wo; dst = woT; N = DMODEL; bid -= 960; }
    const int ntx = N >> 5;
    const int k0 = (bid / ntx) << 5, n0 = (bid % ntx) << 5;
    const int x = threadIdx.x & 31, y = threadIdx.x >> 5;
#pragma unroll
    for (int i = 0; i < 32; i += 8)
        t[y + i][x] = src[(long)(k0 + y + i) * N + n0 + x];
    __syncthreads();
#pragma unroll
    for (int i = 0; i < 32; i += 8)
        dst[(long)(n0 + y + i) * DMODEL + k0 + x] = f2bs(t[x][y + i]);
}

// ---------------------------------------------------------------------------
// V^T prep, PANELED: out_v (B,NKV,SEQ,64) fp32 ->
// Vt[bkv][t>>6][d][t&63] bf16 (each 64-key panel = 8 KB contiguous).
// ---------------------------------------------------------------------------
__global__ __launch_bounds__(256) void vtransp(const float* __restrict__ in,
                                               short* __restrict__ out) {
    __shared__ float t[32][33];
    const long bkv = blockIdx.z;
    const float* ip = in + bkv * SEQ * DHEAD;
    short* op = out + bkv * DHEAD * SEQ;
    const int t0 = blockIdx.x * 32, d0 = blockIdx.y * 32;
    const int x = threadIdx.x & 31, y = threadIdx.x >> 5;
#pragma unroll
    for (int i = 0; i < 32; i += 8)
        t[y + i][x] = ip[(long)(t0 + y + i) * DHEAD + d0 + x];
    __syncthreads();
    const int pan = t0 >> 6, tin = t0 & 63;  // uniform for x<32
#pragma unroll
    for (int i = 0; i < 32; i += 8)
        op[(long)pan * 4096 + (d0 + y + i) * 64 + tin + x] = f2bs(t[x][y + i]);
}

// ---------------------------------------------------------------------------
// MFMA GEMM (TN): C = A[M,K] @ Bt[N,K]^T, fp32 accumulate.
// MODE 0: plain fp32 C.  MODE 1: 3-way split (Q / K cache / V cache).
// ---------------------------------------------------------------------------
#define LST 40

template <typename TA, int MODE>
__global__ __launch_bounds__(256) void gemm_tn(const TA* __restrict__ A,
                                               const short* __restrict__ Bt,
                                               float* __restrict__ Cq,
                                               float* __restrict__ Ck,
                                               float* __restrict__ Cv,
                                               int M, int N, int K) {
    __shared__ short As_[128 * LST];
    __shared__ short Bs_[128 * LST];
    const int tid = threadIdx.x;
    const int lane = tid & 63, w = tid >> 6;
    const int m_ = lane & 15, quad = lane >> 4;
    const int wm = w >> 1, wn = w & 1;
    const long bm = (long)blockIdx.y * 128, bn = (long)blockIdx.x * 128;
    const int sr = tid >> 1, sh = (tid & 1) * 16;

    f32x4 acc[4][4];
#pragma unroll
    for (int i = 0; i < 4; ++i)
#pragma unroll
        for (int j = 0; j < 4; ++j) acc[i][j] = (f32x4){0.f, 0.f, 0.f, 0.f};

    for (int k0 = 0; k0 < K; k0 += 32) {
        short av[16], bv[16];
        if (sizeof(TA) == 4) {
            const float* ap = (const float*)A + (bm + sr) * K + k0 + sh;
            float ff[16];
#pragma unroll
            for (int i = 0; i < 4; ++i) *(float4*)&ff[4 * i] = ((const float4*)ap)[i];
#pragma unroll
            for (int i = 0; i < 16; ++i) av[i] = f2bs(ff[i]);
        } else {
            const short* ap = (const short*)A + (bm + sr) * K + k0 + sh;
            *(uint4*)&av[0] = ((const uint4*)ap)[0];
            *(uint4*)&av[8] = ((const uint4*)ap)[1];
        }
        {
            const short* bp = Bt + (bn + sr) * K + k0 + sh;
            *(uint4*)&bv[0] = ((const uint4*)bp)[0];
            *(uint4*)&bv[8] = ((const uint4*)bp)[1];
        }
        __syncthreads();
        short* ad = &As_[sr * LST + sh];
        short* bd = &Bs_[sr * LST + sh];
#pragma unroll
        for (int i = 0; i < 4; ++i) {
            ((uint2*)ad)[i] = ((uint2*)av)[i];
            ((uint2*)bd)[i] = ((uint2*)bv)[i];
        }
        __syncthreads();

        short8 af[4], bf[4];
#pragma unroll
        for (int i = 0; i < 4; ++i)
            af[i] = *(const short8*)&As_[(wm * 64 + i * 16 + m_) * LST + quad * 8];
#pragma unroll
        for (int j = 0; j < 4; ++j)
            bf[j] = *(const short8*)&Bs_[(wn * 64 + j * 16 + m_) * LST + quad * 8];
#pragma unroll
        for (int i = 0; i < 4; ++i)
#pragma unroll
            for (int j = 0; j < 4; ++j)
                acc[i][j] = __builtin_amdgcn_mfma_f32_16x16x32_bf16(af[i], bf[j], acc[i][j], 0, 0, 0);
    }

#pragma unroll
    for (int i = 0; i < 4; ++i) {
        const int row0 = (int)bm + wm * 64 + i * 16 + quad * 4;
#pragma unroll
        for (int j = 0; j < 4; ++j) {
            const int col = (int)bn + wn * 64 + j * 16 + m_;
#pragma unroll
            for (int r = 0; r < 4; ++r) {
                const int rw = row0 + r;
                const float val = acc[i][j][r];
                if (MODE == 1) {
                    if (col < DMODEL) {
                        Cq[(long)rw * DMODEL + col] = val;
                    } else {
                        const int c2 = col - DMODEL;
                        const int hh = (c2 >> 6) & 3, d = c2 & 63;
                        long oidx = (((long)((rw >> 11) * NKV + hh) * SEQ + (rw & (SEQ - 1))) << 6) | d;
                        ((c2 >> 8) ? Cv : Ck)[oidx] = val;
                    }
                } else {
                    Cq[(long)rw * N + col] = val;
                }
            }
        }
    }
}

// ---------------------------------------------------------------------------
// RoPE: Q fp32 -> bf16 Qb (1/8 scale); K fp32 in place + bf16 copy Kb.
// ---------------------------------------------------------------------------
__global__ void rope_f(const float* __restrict__ Qi, short* __restrict__ Qb,
                       float* Kc, short* Kb) {
    int tid = blockIdx.x * blockDim.x + threadIdx.x;
    int j = tid & 31;
    int head = (tid >> 5) & 15;
    int row = tid >> 9;
    int t = row & (SEQ - 1);
    int b = row >> 11;
    float inv = expf(-(float)j * 0.2878231366f);
    float s, c;
    sincosf((float)t * inv, &s, &c);
    if (head < NHEADS) {
        const float* p = Qi + (long)row * DMODEL + head * DHEAD;
        short* q = Qb + (long)row * DMODEL + head * DHEAD;
        float x1 = p[j], x2 = p[j + 32];
        q[j] = f2bs((x1 * c - x2 * s) * 0.125f);
        q[j + 32] = f2bs((x2 * c + x1 * s) * 0.125f);
    } else {
        const long off = ((long)(b * NKV + (head - NHEADS)) * SEQ + t) << 6;
        float* p = Kc + off;
        float x1 = p[j], x2 = p[j + 32];
        float y1 = x1 * c - x2 * s, y2 = x2 * c + x1 * s;
        p[j] = y1;
        p[j + 32] = y2;
        Kb[off + j] = f2bs(y1);
        Kb[off + j + 32] = f2bs(y2);
    }
}

// ---------------------------------------------------------------------------
// Flash v7: BARRIER-FREE. K/V caches total 4 MB bf16 -> fully L2-resident,
// so LDS staging was pure overhead (barrier-coupled 6 waves + bank conflicts).
// Each wave reads its K/V MFMA fragments straight from global (L1 serves the
// 6-way intra-block reuse). Only per-wave Pl (P^T transpose) stays in LDS ->
// zero __syncthreads in the kernel. V-frag loads issue at tile start; their
// latency hides under QK^T + softmax. Defer-rescale: skip of*=alpha pass when
// tile max doesn't grow (alpha==1 exactly -> no numeric change).
// ---------------------------------------------------------------------------
#define KST 72

__global__ __launch_bounds__(384, 3) void flash6(
    const short* __restrict__ Qb, const short* __restrict__ Kb,
    const short* __restrict__ Vt, short* __restrict__ ATT) {
    __shared__ short Pl[6][16 * KST];
    const int tid = threadIdx.x;
    const int w = tid >> 6, lane = tid & 63;
    const int m_ = lane & 15, quad = lane >> 4;
    const int bkv = blockIdx.x >> 6;
    const int t0 = (63 - (blockIdx.x & 63)) << 5;   // heavy blocks first
    const int b = bkv >> 2, kvh = bkv & 3;
    const int h = kvh * 3 + (w >> 1);
    const int qg = w & 1;
    const int trw = t0 + (qg << 4);
    const int tq = trw + m_;       // this lane's q-row

    // per-lane global fragment base pointers (shorts)
    const short* kp = Kb + (((long)bkv * SEQ) << 6) + m_ * 64 + quad * 8;
    const short* vp = Vt + (long)bkv * SEQ * DHEAD + m_ * 64 + quad * 8;

    // Q B-frags
    const short* qp = Qb + (long)(b * SEQ + tq) * DMODEL + h * DHEAD + quad * 8;
    const short8 qf0 = *(const short8*)qp;
    const short8 qf1 = *(const short8*)(qp + 32);

    f32x4 of[4];
#pragma unroll
    for (int i = 0; i < 4; ++i) of[i] = (f32x4){0.f, 0.f, 0.f, 0.f};
    float mr = -1e30f, lr = 0.f;

    int wlo = t0 - (WIN - 1);      // FIRST row's window floor
    if (wlo < GLB) wlo = GLB;
    wlo &= ~63;
    const int nwin = (t0 + 31 >= wlo) ? (((t0 + 31 - wlo) >> 6) + 1) : 0;
    const int ntile = 1 + nwin;

    for (int tI = 0; tI < ntile; ++tI) {
        const int kb = (tI == 0) ? 0 : (wlo + ((tI - 1) << 6));

        // K frags direct from global (L2-hot)
        const short* kq = kp + ((long)kb << 6);
        short8 kf[8];
#pragma unroll
        for (int st = 0; st < 4; ++st)
#pragma unroll
            for (int hh = 0; hh < 2; ++hh)
                kf[st * 2 + hh] = *(const short8*)(kq + st * 1024 + hh * 32);

        // V frags direct from global — issued now, consumed after softmax
        const short* vq = vp + (((long)kb >> 6) << 12);
        short8 vf[8];
#pragma unroll
        for (int dt = 0; dt < 4; ++dt)
#pragma unroll
            for (int kh = 0; kh < 2; ++kh)
                vf[dt * 2 + kh] = *(const short8*)(vq + dt * 1024 + kh * 32);

        // S^T = K Q^T
        f32x4 s[4];
#pragma unroll
        for (int st = 0; st < 4; ++st) {
            f32x4 a = (f32x4){0.f, 0.f, 0.f, 0.f};
            a = __builtin_amdgcn_mfma_f32_16x16x32_bf16(kf[st * 2 + 0], qf0, a, 0, 0, 0);
            a = __builtin_amdgcn_mfma_f32_16x16x32_bf16(kf[st * 2 + 1], qf1, a, 0, 0, 0);
            s[st] = a;
        }

        const bool fully = (kb + 63 <= trw) &&
                           ((kb >= trw + 16 - WIN) || (kb + 63 < GLB) || (trw + 15 < GLB));
        if (!fully) {
#pragma unroll
            for (int st = 0; st < 4; ++st) {
#pragma unroll
                for (int r = 0; r < 4; ++r) {
                    const int key = kb + st * 16 + quad * 4 + r;
                    const bool ok = (key <= tq) && ((key > tq - WIN) || (key < GLB) || (tq < GLB));
                    if (!ok) s[st][r] = -1e30f;
                }
            }
        }

        // online softmax (per-lane; 2 shuffles across quad replicas)
        float tm = -1e30f;
#pragma unroll
        for (int st = 0; st < 4; ++st)
#pragma unroll
            for (int r = 0; r < 4; ++r) tm = fmaxf(tm, s[st][r]);
        tm = fmaxf(tm, __shfl_xor(tm, 16, 64));
        tm = fmaxf(tm, __shfl_xor(tm, 32, 64));
        // defer-rescale: only pay the O/l rescale when the max actually grows
        if (!__all(tm <= mr)) {
            const float mnew = fmaxf(mr, tm);
            const float alpha = __expf(mr - mnew);
            mr = mnew;
            lr *= alpha;
#pragma unroll
            for (int dt = 0; dt < 4; ++dt)
#pragma unroll
                for (int r = 0; r < 4; ++r) of[dt][r] *= alpha;
        }
        float rs = 0.f;
#pragma unroll
        for (int st = 0; st < 4; ++st) {
            float p0 = __expf(s[st][0] - mr);
            float p1 = __expf(s[st][1] - mr);
            float p2 = __expf(s[st][2] - mr);
            float p3 = __expf(s[st][3] - mr);
            rs += (p0 + p1) + (p2 + p3);
            union { short sh[4]; unsigned long long u; } pk;
            pk.sh[0] = f2bs(p0); pk.sh[1] = f2bs(p1);
            pk.sh[2] = f2bs(p2); pk.sh[3] = f2bs(p3);
            *(unsigned long long*)&Pl[w][m_ * KST + st * 16 + quad * 4] = pk.u;
        }
        rs += __shfl_xor(rs, 16, 64);
        rs += __shfl_xor(rs, 32, 64);
        lr += rs;

        // P^T B-frags via per-wave LDS (same wave writes+reads: no barrier)
        short8 pf[2];
#pragma unroll
        for (int kh = 0; kh < 2; ++kh)
            pf[kh] = *(const short8*)&Pl[w][m_ * KST + kh * 32 + quad * 8];

        // O^T += V^T P^T
#pragma unroll
        for (int dt = 0; dt < 4; ++dt) {
            of[dt] = __builtin_amdgcn_mfma_f32_16x16x32_bf16(vf[dt * 2 + 0], pf[0], of[dt], 0, 0, 0);
            of[dt] = __builtin_amdgcn_mfma_f32_16x16x32_bf16(vf[dt * 2 + 1], pf[1], of[dt], 0, 0, 0);
        }
    }

    // epilogue
    const float inv = 1.0f / lr;
    short* op = ATT + (long)(b * SEQ + tq) * DMODEL + h * DHEAD + quad * 4;
#pragma unroll
    for (int dt = 0; dt < 4; ++dt) {
        union { short sh[4]; unsigned long long u; } pk;
#pragma unroll
        for (int r = 0; r < 4; ++r) pk.sh[r] = f2bs(of[dt][r] * inv);
        *(unsigned long long*)(op + dt * 16) = pk.u;
    }
}

// ---------------------------------------------------------------------------
extern "C" void kernel_launch(void* const* d_in, const int* in_sizes, int n_in,
                              void* d_out, int out_size, void* d_ws, size_t ws_size,
                              hipStream_t stream) {
    const float* x = (const float*)d_in[0];
    const float* wq = (const float*)d_in[1];
    const float* wk = (const float*)d_in[2];
    const float* wv = (const float*)d_in[3];
    const float* wo = (const float*)d_in[4];
    float* out = (float*)d_out;
    float* out_k = out + (long)ROWS * DMODEL;
    float* out_v = out_k + (long)BATCH * NKV * SEQ * DHEAD;

    // ws (shorts), 11.125 MiB: region A: wqkvT -> Qb -> ATTb (sequential lifetimes)
    short* regA = (short*)d_ws;
    short* wqkvT = regA;
    short* Qb = regA;
    short* ATTb = regA;
    short* woT = regA + (long)ROWS * DMODEL;
    short* KbB = woT + (long)DMODEL * DMODEL;
    short* VtB = KbB + (long)BATCH * NKV * SEQ * DHEAD;

    transp_all<<<1536, 256, 0, stream>>>(wq, wk, wv, wo, wqkvT, woT);
    gemm_tn<float, 1><<<dim3((DMODEL + 2 * NKV * DHEAD) / 128, ROWS / 128), 256, 0, stream>>>(
        x, wqkvT, out, out_k, out_v, ROWS, DMODEL + 2 * NKV * DHEAD, DMODEL);
    rope_f<<<(ROWS * 16 * 32) / 256, 256, 0, stream>>>(out, Qb, out_k, KbB);
    vtransp<<<dim3(SEQ / 32, DHEAD / 32, BATCH * NKV), 256, 0, stream>>>(out_v, VtB);
    flash6<<<BATCH * NKV * (SEQ / 32), 384, 0, stream>>>(Qb, KbB, VtB, ATTb);
    gemm_tn<short, 0><<<dim3(DMODEL / 128, ROWS / 128), 256, 0, stream>>>(
        ATTb, woT, out, nullptr, nullptr, ROWS, DMODEL, DMODEL);
}